// Round 14
// baseline (177.540 us; speedup 1.0000x reference)
//
#include <hip/hip_runtime.h>
#include <hip/hip_bf16.h>

typedef unsigned int u32;
typedef unsigned short u16;
typedef short bf16x8 __attribute__((ext_vector_type(8)));
typedef float f32x4 __attribute__((ext_vector_type(4)));
typedef float f32x2 __attribute__((ext_vector_type(2)));

#define LQ 11     // sequence length
#define RPB 8     // batch rows per block
#define NR 88     // real samples per side (8*11)
// proj row = 32 u16 = 64 B = 4 chunks of 16 B; physical chunk = logical ^ (row&3)

// d_ws layout (u16 elements): pre-packed bf16 tables, rebuilt every call
#define EMB_OFF   0         // 10000*16
#define PEMB_OFF  160000    // 16*16
#define H2AW_OFF  160256    // 96*32
#define A2HW_OFF  163328    // 96*32
#define PACK_N    166400    // total u16 elements -> 332800 B

__device__ __forceinline__ float blo(u32 x) { return __uint_as_float(x << 16); }
__device__ __forceinline__ float bhi(u32 x) { return __uint_as_float(x & 0xFFFF0000u); }
__device__ __forceinline__ float bf1(u16 x) { return __uint_as_float(((u32)x) << 16); }
__device__ __forceinline__ f32x2 kf2(u32 x) { return (f32x2){ blo(x), bhi(x) }; }
__device__ __forceinline__ u16 f2b(float f) {
    __hip_bfloat16 h = __float2bfloat16(f);
    return *reinterpret_cast<u16*>(&h);
}
__device__ __forceinline__ u32 pk2(float a, float b) {
    return (u32)f2b(a) | ((u32)f2b(b) << 16);
}

// DPP cross-lane: VALU-pipe lane exchange, no LDS traffic, no address setup.
template<int CTRL>
__device__ __forceinline__ float dppf(float x) {
    return __int_as_float(__builtin_amdgcn_update_dpp(
        0, __float_as_int(x), CTRL, 0xF, 0xF, true));
}
// Butterfly sum within each 16-lane row (== shfl_xor 1,2,4,8 over width 16).
__device__ __forceinline__ float qsum16(float v) {
    v += dppf<0xB1>(v);   // quad_perm [1,0,3,2]  (xor 1)
    v += dppf<0x4E>(v);   // quad_perm [2,3,0,1]  (xor 2)
    v += dppf<0x124>(v);  // row_ror:4
    v += dppf<0x128>(v);  // row_ror:8
    return v;
}

// ---------- kernel 1: convert f32 tables -> bf16 in d_ws (trivial, ~5us) ----------
__global__ __launch_bounds__(256)
void pack_tables(const float* __restrict__ emb, const float* __restrict__ pemb,
                 const float* __restrict__ h2a_w, const float* __restrict__ a2h_w,
                 u16* __restrict__ ws)
{
    const int i = blockIdx.x * 256 + threadIdx.x;
    if (i >= PACK_N) return;
    const float* src; int off;
    if (i < PEMB_OFF)      { src = emb;   off = EMB_OFF; }
    else if (i < H2AW_OFF) { src = pemb;  off = PEMB_OFF; }
    else if (i < A2HW_OFF) { src = h2a_w; off = H2AW_OFF; }
    else                   { src = a2h_w; off = A2HW_OFF; }
    ws[i] = f2b(src[i - off]);
}

// ---------- kernel 2: main (v14 = v13 + Phase-D split + tree softmax sum) ----
__global__ __launch_bounds__(512, 6)
void CrossTeam_v14(const int* __restrict__ home, const int* __restrict__ away,
                   const int* __restrict__ hpos, const int* __restrict__ apos,
                   const u16* __restrict__ wsb,
                   const float* __restrict__ h2a_b,
                   const float* __restrict__ h2a_ow, const float* __restrict__ h2a_ob,
                   const float* __restrict__ a2h_b,
                   const float* __restrict__ a2h_ow, const float* __restrict__ a2h_ob,
                   const float* __restrict__ gw, const float* __restrict__ gb,
                   const float* __restrict__ lnw, const float* __restrict__ lnb,
                   float* __restrict__ out)
{
    // proj: 0=Qh 1=Kh 2=Vh 3=Qa 4=Ka 5=Va (bf16, bias folded, sample-major,
    // 16B chunks XOR-swizzled by row&3)
    __shared__ u16 proj[6][NR * 32];          // 33792 B
    __shared__ union {
        int ptab[2][NR][2];                   // 2816 B (Phase A-B): {player, pos}
        struct {                              // 4096 B (Phase C-D)
            float obuf[2][RPB][32];
            float ybuf[2][RPB][32];
        } cd;
    } u;
    __shared__ u32 mraw[2][RPB];              //    64 B   -> 37952 B total

    const int t = threadIdx.x;
    const int b0 = blockIdx.x * RPB;

    // ---- Phase A: stage indices + padding masks ----
    if (t < 176) {
        const int side = t / 88;              // 0 = home, 1 = away
        const int s = t - side * 88;          // sample = r*11 + l
        const int r = s / 11, l = s - r * 11;
        const int gi = (b0 + r) * LQ + l;
        u.ptab[side][s][0] = side ? away[gi] : home[gi];
        u.ptab[side][s][1] = side ? apos[gi] : hpos[gi];
    }
    if (t >= 496) {
        const int k = t - 496; const int side = k >> 3; const int r = k & 7;
        const int* arr = side ? away : home;
        u32 m = 0;
        for (int l = 0; l < LQ; ++l) m |= (u32)(arr[(b0 + r) * LQ + l] == 0) << l;
        mraw[side][r] = m;
    }
    __syncthreads();

    const int wave = t >> 6, lane = t & 63;
    const int lq = lane >> 4, lm = lane & 15;  // quad, in-tile index

    // ---- Phase B: QKV projections via MFMA; fragments load pre-packed bf16 ----
    {
        const int side = wave >> 2;            // which x-vectors (0=h, 1=a)
        const int mh = (wave >> 1) & 1;        // M-tile half
        const int nh = wave & 1;               // N-tile half
        // h-vectors: Q from h2a.Wq, K/V from a2h.Wk/Wv; a-vectors vice versa
        const u16* wq_src  = wsb + (side ? A2HW_OFF : H2AW_OFF);
        const u16* wkv_src = wsb + (side ? H2AW_OFF : A2HW_OFF);
        const float* bq_src  = side ? a2h_b : h2a_b;
        const float* bkv_src = side ? h2a_b : a2h_b;
        bf16x8 afrag[3]; float bias[3][4];
        #pragma unroll
        for (int i = 0; i < 3; ++i) {
            const int M = (mh * 3 + i) * 16;
            const u16* wsrc = (M < 32) ? wq_src : wkv_src;
            afrag[i] = *(const bf16x8*)(wsrc + (M + lm) * 32 + lq * 8);
            const float* bs = (M < 32) ? bq_src : bkv_src;
            #pragma unroll
            for (int j = 0; j < 4; ++j) bias[i][j] = bs[M + lq * 4 + j];
        }
        bf16x8 bfrag[3];
        #pragma unroll
        for (int nn = 0; nn < 3; ++nn) {
            const int srow = (nh * 3 + nn) * 16 + lm;
            const int s = srow < NR ? srow : NR - 1;     // cols >=88 discarded at store
            const int id = u.ptab[side][s][lq >> 1];     // quads 0-1: player, 2-3: pos
            bfrag[nn] = *(const bf16x8*)
                (wsb + ((lq < 2) ? EMB_OFF : PEMB_OFF) + id * 16 + (lq & 1) * 8);
        }
        #pragma unroll
        for (int nn = 0; nn < 3; ++nn) {
            const int srow = (nh * 3 + nn) * 16 + lm;
            #pragma unroll
            for (int i = 0; i < 3; ++i) {
                f32x4 acc = { bias[i][0], bias[i][1], bias[i][2], bias[i][3] };
                acc = __builtin_amdgcn_mfma_f32_16x16x32_bf16(afrag[i], bfrag[nn], acc, 0, 0, 0);
                const int mt = mh * 3 + i;
                const int mat = side * 3 + (mt >> 1);      // Q/K/V of this side
                const int dimw = (mt & 1) * 16 + lq * 4;   // u16 index within 32
                if (srow < NR) {
                    const int phys = srow * 32 + ((((dimw >> 3) ^ srow) & 3) << 3) + (dimw & 7);
                    uint2 pk;
                    pk.x = pk2(acc[0], acc[1]);
                    pk.y = pk2(acc[2], acc[3]);
                    *(uint2*)&proj[mat][phys] = pk;
                }
            }
        }
    }
    __syncthreads();

    // ---- Phase C: attention + query-mean aggregation, lane = (head, qi) ----
    // ki regrouped by kb = ki mod 4: same swizzle phase -> base ptr + m*256B
    // immediate offsets. Dot in f32x2 (pk-f32 path). Softmax sum: balanced tree
    // after the loop (breaks the 11-deep add chain coupled to exp latency).
    {
        const int hh = lane >> 4;              // head
        const int slot = lane & 15;            // qi slot (>=11 inactive)
        const int qi = slot < 11 ? slot : 10;  // clamped for safe loads
        const int dpv = hh * 8 + (slot & 7);   // PV output dim for this lane
        #pragma unroll
        for (int it = 0; it < 2; ++it) {
            const int task = wave * 2 + it;               // 16 tasks over 8 waves
            const int r = task >> 1, dir = task & 1;      // 0: h2a, 1: a2h
            const int qmat = dir ? 3 : 0;
            const int kmat = dir ? 1 : 4;
            const int vmat = dir ? 2 : 5;
            const int r11 = r * 11;
            const u32 kvraw = mraw[dir ? 0 : 1][r];       // KV-side padding mask
            const u32 kv = (kvraw == 0x7FFu) ? 0u : kvraw;   // safe_mask
            const u32 qraw = mraw[dir ? 1 : 0][r];        // query-side mask
            const u32 smq = (qraw == 0x7FFu) ? 0u : qraw;
            const u32 vm = (~smq) & 0x7FFu;               // valid queries (never empty)
            const float invc = 1.0f / (float)__popc(vm);
            const float wqw = (slot < 11 && ((vm >> slot) & 1u)) ? invc : 0.f;
            const int qrow = r11 + qi;
            const uint4 qp = *(const uint4*)&proj[qmat][qrow * 32 + (((hh ^ qrow) & 3) << 3)];
            const f32x2 sc2 = { 0.35355339059327373f, 0.35355339059327373f };
            f32x2 qv2[4];                                  // 1/sqrt(8) pre-folded
            qv2[0] = kf2(qp.x) * sc2; qv2[1] = kf2(qp.y) * sc2;
            qv2[2] = kf2(qp.z) * sc2; qv2[3] = kf2(qp.w) * sc2;
            float e[11];
            #pragma unroll
            for (int kb = 0; kb < 4; ++kb) {
                const int krow0 = r11 + kb;
                const u16* kbp = &proj[kmat][krow0 * 32 + (((hh ^ krow0) & 3) << 3)];
                #pragma unroll
                for (int m = 0; m < 3; ++m) {
                    const int ki = kb + 4 * m;            // compile-time constant
                    if (ki < 11) {
                        const uint4 kp = *(const uint4*)(kbp + m * 128);  // +256B imm
                        f32x2 acc = qv2[0] * kf2(kp.x);
                        acc += qv2[1] * kf2(kp.y);
                        acc += qv2[2] * kf2(kp.z);
                        acc += qv2[3] * kf2(kp.w);
                        const float s = acc[0] + acc[1];
                        e[ki] = ((kv >> ki) & 1u) ? 0.f : __expf(s);  // exact exp(-inf)=0
                    }
                }
            }
            // balanced tree: depth 4 instead of an 11-deep serial chain
            const float sum = (((e[0] + e[1]) + (e[2] + e[3]))
                             + ((e[4] + e[5]) + (e[6] + e[7])))
                             + ((e[8] + e[9]) + e[10]);
            const float rs = wqw / fmaxf(sum, 1e-20f);    // fold aggregation weight in
            float o = 0.f;
            #pragma unroll
            for (int kb = 0; kb < 4; ++kb) {
                const int krow0 = r11 + kb;
                const u16* vbp = &proj[vmat][krow0 * 32 + (((hh ^ krow0) & 3) << 3) + (slot & 7)];
                #pragma unroll
                for (int m = 0; m < 3; ++m) {
                    const int ki = kb + 4 * m;
                    if (ki < 11) {
                        // sum w_q * p over the 16 qi slots: DPP butterfly (VALU-only)
                        const float v = qsum16(e[ki] * rs);
                        o += v * bf1(vbp[m * 128]);       // +256B imm offset
                    }
                }
            }
            if (slot < 8) u.cd.obuf[dir][r][dpv] = o;     // 32 dims per task
        }
    }
    __syncthreads();

    // ---- Phase D1: out-proj split across ALL 8 waves (half: yh, half: ya) ----
    {
        const int half = t >> 8;               // 0: yh (h2a), 1: ya (a2h)
        const int tt = t & 255;
        const int r = tt >> 5, d = tt & 31;
        float y = half ? a2h_ob[d] : h2a_ob[d];
        const f32x4* w0 = (const f32x4*)((half ? a2h_ow : h2a_ow) + d * 32);
        const f32x4* o0 = (const f32x4*)&u.cd.obuf[half][r][0];
        #pragma unroll
        for (int c = 0; c < 8; ++c) {
            const f32x4 a = o0[c], b = w0[c];
            y += a[0]*b[0] + a[1]*b[1] + a[2]*b[2] + a[3]*b[3];
        }
        u.cd.ybuf[half][r][d] = y;
    }
    __syncthreads();

    // ---- Phase D2: gate + LayerNorm (threads 0..255) ----
    if (t < 256) {
        const int r = t >> 5, d = t & 31;
        const float yh = u.cd.ybuf[0][r][d];
        const float ya = u.cd.ybuf[1][r][d];
        float acc = gb[d];
        {
            const f32x4* g0 = (const f32x4*)(gw + d * 64);
            const f32x4* y0 = (const f32x4*)&u.cd.ybuf[0][r][0];
            const f32x4* y1 = (const f32x4*)&u.cd.ybuf[1][r][0];
            #pragma unroll
            for (int c = 0; c < 8; ++c) {
                const f32x4 a = y0[c], b = g0[c], p = y1[c], q = g0[8 + c];
                acc += a[0]*b[0] + a[1]*b[1] + a[2]*b[2] + a[3]*b[3];
                acc += p[0]*q[0] + p[1]*q[1] + p[2]*q[2] + p[3]*q[3];
            }
        }
        const float g = 1.0f / (1.0f + __expf(-acc));
        const float m = g * yh + (1.0f - g) * ya;
        // 32-wide reduction: DPP within 16, one shuffle across the halves
        float s1 = qsum16(m), s2 = qsum16(m * m);
        s1 += __shfl_xor(s1, 16, 32);
        s2 += __shfl_xor(s2, 16, 32);
        const float mu = s1 * 0.03125f;
        const float var = fmaxf(s2 * 0.03125f - mu * mu, 0.f);
        const float res = (m - mu) * rsqrtf(var + 1e-5f) * lnw[d] + lnb[d];
        out[(b0 + r) * 32 + d] = res;
    }
}

// ---------- fallback (ws too small): proven v9, byte-identical ----------
__global__ __launch_bounds__(512, 6)
void CrossTeam_v9fb(const int* __restrict__ home, const int* __restrict__ away,
                    const int* __restrict__ hpos, const int* __restrict__ apos,
                    const float* __restrict__ emb, const float* __restrict__ pemb,
                    const float* __restrict__ h2a_w, const float* __restrict__ h2a_b,
                    const float* __restrict__ h2a_ow, const float* __restrict__ h2a_ob,
                    const float* __restrict__ a2h_w, const float* __restrict__ a2h_b,
                    const float* __restrict__ a2h_ow, const float* __restrict__ a2h_ob,
                    const float* __restrict__ gw, const float* __restrict__ gb,
                    const float* __restrict__ lnw, const float* __restrict__ lnb,
                    float* __restrict__ out)
{
    __shared__ u16 proj[6][NR * 32];
    __shared__ union {
        int ptab[2][NR][2];
        struct { float obuf[2][RPB][32]; float ybuf[2][RPB][32]; } cd;
    } u;
    __shared__ u32 mraw[2][RPB];
    const int t = threadIdx.x;
    const int b0 = blockIdx.x * RPB;
    if (t < 176) {
        const int side = t / 88, s = t - side * 88;
        const int r = s / 11, l = s - r * 11;
        const int gi = (b0 + r) * LQ + l;
        u.ptab[side][s][0] = side ? away[gi] : home[gi];
        u.ptab[side][s][1] = side ? apos[gi] : hpos[gi];
    }
    if (t >= 496) {
        const int k = t - 496; const int side = k >> 3; const int r = k & 7;
        const int* arr = side ? away : home;
        u32 m = 0;
        for (int l = 0; l < LQ; ++l) m |= (u32)(arr[(b0 + r) * LQ + l] == 0) << l;
        mraw[side][r] = m;
    }
    __syncthreads();
    const int wave = t >> 6, lane = t & 63;
    const int lq = lane >> 4, lm = lane & 15;
    {
        const int side = wave >> 2, mh = (wave >> 1) & 1, nh = wave & 1;
        const float* wq_src  = side ? a2h_w : h2a_w;
        const float* wkv_src = side ? h2a_w : a2h_w;
        const float* bq_src  = side ? a2h_b : h2a_b;
        const float* bkv_src = side ? h2a_b : a2h_b;
        bf16x8 afrag[3]; float bias[3][4];
        #pragma unroll
        for (int i = 0; i < 3; ++i) {
            const int M = (mh * 3 + i) * 16;
            const float* ws = (M < 32) ? wq_src : wkv_src;
            const float* wp = ws + (M + lm) * 32 + lq * 8;
            const f32x4 a0 = *(const f32x4*)wp;
            const f32x4 a1 = *(const f32x4*)(wp + 4);
            union { bf16x8 v; u32 w[4]; } au;
            au.w[0] = pk2(a0[0], a0[1]); au.w[1] = pk2(a0[2], a0[3]);
            au.w[2] = pk2(a1[0], a1[1]); au.w[3] = pk2(a1[2], a1[3]);
            afrag[i] = au.v;
            const float* bs = (M < 32) ? bq_src : bkv_src;
            #pragma unroll
            for (int j = 0; j < 4; ++j) bias[i][j] = bs[M + lq * 4 + j];
        }
        bf16x8 bfrag[3];
        #pragma unroll
        for (int nn = 0; nn < 3; ++nn) {
            const int srow = (nh * 3 + nn) * 16 + lm;
            const int s = srow < NR ? srow : NR - 1;
            const int id = u.ptab[side][s][lq >> 1];
            const float* gp = ((lq < 2) ? emb : pemb) + id * 16 + (lq & 1) * 8;
            const f32x4 g0 = *(const f32x4*)gp;
            const f32x4 g1 = *(const f32x4*)(gp + 4);
            union { bf16x8 v; u32 w[4]; } bu;
            bu.w[0] = pk2(g0[0], g0[1]); bu.w[1] = pk2(g0[2], g0[3]);
            bu.w[2] = pk2(g1[0], g1[1]); bu.w[3] = pk2(g1[2], g1[3]);
            bfrag[nn] = bu.v;
        }
        #pragma unroll
        for (int nn = 0; nn < 3; ++nn) {
            const int srow = (nh * 3 + nn) * 16 + lm;
            #pragma unroll
            for (int i = 0; i < 3; ++i) {
                f32x4 acc = { bias[i][0], bias[i][1], bias[i][2], bias[i][3] };
                acc = __builtin_amdgcn_mfma_f32_16x16x32_bf16(afrag[i], bfrag[nn], acc, 0, 0, 0);
                const int mt = mh * 3 + i;
                const int mat = side * 3 + (mt >> 1);
                const int dimw = (mt & 1) * 16 + lq * 4;
                if (srow < NR) {
                    const int phys = srow * 32 + ((((dimw >> 3) ^ srow) & 3) << 3) + (dimw & 7);
                    uint2 pk; pk.x = pk2(acc[0], acc[1]); pk.y = pk2(acc[2], acc[3]);
                    *(uint2*)&proj[mat][phys] = pk;
                }
            }
        }
    }
    __syncthreads();
    {
        const int hh = lane >> 4, slot = lane & 15;
        const int qi = slot < 11 ? slot : 10;
        const int dpv = hh * 8 + (slot & 7);
        #pragma unroll
        for (int it = 0; it < 2; ++it) {
            const int task = wave * 2 + it;
            const int r = task >> 1, dir = task & 1;
            const int qmat = dir ? 3 : 0, kmat = dir ? 1 : 4, vmat = dir ? 2 : 5;
            const int r11 = r * 11;
            const u32 kvraw = mraw[dir ? 0 : 1][r];
            const u32 kv = (kvraw == 0x7FFu) ? 0u : kvraw;
            const u32 qraw = mraw[dir ? 1 : 0][r];
            const u32 smq = (qraw == 0x7FFu) ? 0u : qraw;
            const u32 vm = (~smq) & 0x7FFu;
            const float invc = 1.0f / (float)__popc(vm);
            const float wqw = (slot < 11 && ((vm >> slot) & 1u)) ? invc : 0.f;
            const int qrow = r11 + qi;
            const uint4 qp = *(const uint4*)&proj[qmat][qrow * 32 + (((hh ^ qrow) & 3) << 3)];
            float qv[8];
            qv[0]=blo(qp.x); qv[1]=bhi(qp.x); qv[2]=blo(qp.y); qv[3]=bhi(qp.y);
            qv[4]=blo(qp.z); qv[5]=bhi(qp.z); qv[6]=blo(qp.w); qv[7]=bhi(qp.w);
            float e[11]; float sum = 0.f;
            #pragma unroll
            for (int ki = 0; ki < 11; ++ki) {
                const int krow = r11 + ki;
                const uint4 kp = *(const uint4*)&proj[kmat][krow * 32 + (((hh ^ krow) & 3) << 3)];
                float s = qv[0]*blo(kp.x) + qv[1]*bhi(kp.x) + qv[2]*blo(kp.y) + qv[3]*bhi(kp.y)
                        + qv[4]*blo(kp.z) + qv[5]*bhi(kp.z) + qv[6]*blo(kp.w) + qv[7]*bhi(kp.w);
                s *= 0.35355339059327373f;
                e[ki] = ((kv >> ki) & 1u) ? 0.f : __expf(s);
                sum += e[ki];
            }
            const float rs = wqw / fmaxf(sum, 1e-20f);
            float o = 0.f;
            #pragma unroll
            for (int ki = 0; ki < 11; ++ki) {
                float v = e[ki] * rs;
                v += __shfl_xor(v, 1, 16); v += __shfl_xor(v, 2, 16);
                v += __shfl_xor(v, 4, 16); v += __shfl_xor(v, 8, 16);
                const int vrow = r11 + ki;
                o += v * bf1(proj[vmat][vrow * 32 + (((hh ^ vrow) & 3) << 3) + (slot & 7)]);
            }
            if (slot < 8) u.cd.obuf[dir][r][dpv] = o;
        }
    }
    __syncthreads();
    if (t < 256) {
        const int r = t >> 5, d = t & 31;
        float yh = h2a_ob[d];
        const float* wr = h2a_ow + d * 32;
        #pragma unroll
        for (int c = 0; c < 32; ++c) yh += u.cd.obuf[0][r][c] * wr[c];
        float ya = a2h_ob[d];
        wr = a2h_ow + d * 32;
        #pragma unroll
        for (int c = 0; c < 32; ++c) ya += u.cd.obuf[1][r][c] * wr[c];
        u.cd.ybuf[0][r][d] = yh; u.cd.ybuf[1][r][d] = ya;
        float acc = gb[d];
        const float* gr = gw + d * 64;
        #pragma unroll
        for (int c = 0; c < 32; ++c) acc += u.cd.ybuf[0][r][c] * gr[c];
        #pragma unroll
        for (int c = 0; c < 32; ++c) acc += u.cd.ybuf[1][r][c] * gr[32 + c];
        const float g = 1.0f / (1.0f + __expf(-acc));
        const float m = g * yh + (1.0f - g) * ya;
        float s1 = m, s2 = m * m;
        #pragma unroll
        for (int off = 1; off < 32; off <<= 1) {
            s1 += __shfl_xor(s1, off, 32); s2 += __shfl_xor(s2, off, 32);
        }
        const float mu = s1 * 0.03125f;
        const float var = fmaxf(s2 * 0.03125f - mu * mu, 0.f);
        out[(b0 + r) * 32 + d] = (m - mu) * rsqrtf(var + 1e-5f) * lnw[d] + lnb[d];
    }
}

extern "C" void kernel_launch(void* const* d_in, const int* in_sizes, int n_in,
                              void* d_out, int out_size, void* d_ws, size_t ws_size,
                              hipStream_t stream) {
    (void)in_sizes; (void)n_in; (void)out_size;
    if (ws_size >= (size_t)PACK_N * 2) {
        pack_tables<<<(PACK_N + 255) / 256, 256, 0, stream>>>(
            (const float*)d_in[4], (const float*)d_in[5],
            (const float*)d_in[6], (const float*)d_in[10], (u16*)d_ws);
        CrossTeam_v14<<<32768 / RPB, 512, 0, stream>>>(
            (const int*)d_in[0], (const int*)d_in[1], (const int*)d_in[2], (const int*)d_in[3],
            (const u16*)d_ws,
            (const float*)d_in[7], (const float*)d_in[8], (const float*)d_in[9],
            (const float*)d_in[11], (const float*)d_in[12], (const float*)d_in[13],
            (const float*)d_in[14], (const float*)d_in[15], (const float*)d_in[16],
            (const float*)d_in[17], (float*)d_out);
    } else {
        CrossTeam_v9fb<<<32768 / RPB, 512, 0, stream>>>(
            (const int*)d_in[0], (const int*)d_in[1], (const int*)d_in[2], (const int*)d_in[3],
            (const float*)d_in[4], (const float*)d_in[5],
            (const float*)d_in[6], (const float*)d_in[7], (const float*)d_in[8], (const float*)d_in[9],
            (const float*)d_in[10], (const float*)d_in[11], (const float*)d_in[12], (const float*)d_in[13],
            (const float*)d_in[14], (const float*)d_in[15], (const float*)d_in[16], (const float*)d_in[17],
            (float*)d_out);
    }
}

// Round 15
// 172.465 us; speedup vs baseline: 1.0294x; 1.0294x over previous
//
#include <hip/hip_runtime.h>
#include <hip/hip_bf16.h>

typedef unsigned int u32;
typedef unsigned short u16;
typedef short bf16x8 __attribute__((ext_vector_type(8)));
typedef float f32x4 __attribute__((ext_vector_type(4)));
typedef float f32x2 __attribute__((ext_vector_type(2)));

#define LQ 11     // sequence length
#define RPB 8     // batch rows per block
#define NR 88     // real samples per side (8*11)
// proj row = 32 u16 = 64 B = 4 chunks of 16 B; physical chunk = logical ^ (row&3)

// d_ws layout (u16 elements): pre-packed bf16 tables, rebuilt every call
#define EMB_OFF   0         // 10000*16
#define PEMB_OFF  160000    // 16*16
#define H2AW_OFF  160256    // 96*32
#define A2HW_OFF  163328    // 96*32
#define PACK_N    166400    // total u16 elements -> 332800 B

__device__ __forceinline__ float blo(u32 x) { return __uint_as_float(x << 16); }
__device__ __forceinline__ float bhi(u32 x) { return __uint_as_float(x & 0xFFFF0000u); }
__device__ __forceinline__ float bf1(u16 x) { return __uint_as_float(((u32)x) << 16); }
__device__ __forceinline__ f32x2 kf2(u32 x) { return (f32x2){ blo(x), bhi(x) }; }
__device__ __forceinline__ u16 f2b(float f) {
    __hip_bfloat16 h = __float2bfloat16(f);
    return *reinterpret_cast<u16*>(&h);
}
__device__ __forceinline__ u32 pk2(float a, float b) {
    return (u32)f2b(a) | ((u32)f2b(b) << 16);
}

// DPP cross-lane: VALU-pipe lane exchange, no LDS traffic, no address setup.
// dpp_ctrl must be an IR constant -> template parameter (rocPRIM idiom).
template<int CTRL>
__device__ __forceinline__ float dppf(float x) {
    return __int_as_float(__builtin_amdgcn_update_dpp(
        0, __float_as_int(x), CTRL, 0xF, 0xF, true));
}
// Butterfly sum within each 16-lane row (== shfl_xor 1,2,4,8 over width 16).
__device__ __forceinline__ float qsum16(float v) {
    v += dppf<0xB1>(v);   // quad_perm [1,0,3,2]  (xor 1)
    v += dppf<0x4E>(v);   // quad_perm [2,3,0,1]  (xor 2)
    v += dppf<0x124>(v);  // row_ror:4
    v += dppf<0x128>(v);  // row_ror:8
    return v;
}

// ---------- kernel 1: convert f32 tables -> bf16 in d_ws (trivial, ~5us) ----------
__global__ __launch_bounds__(256)
void pack_tables(const float* __restrict__ emb, const float* __restrict__ pemb,
                 const float* __restrict__ h2a_w, const float* __restrict__ a2h_w,
                 u16* __restrict__ ws)
{
    const int i = blockIdx.x * 256 + threadIdx.x;
    if (i >= PACK_N) return;
    const float* src; int off;
    if (i < PEMB_OFF)      { src = emb;   off = EMB_OFF; }
    else if (i < H2AW_OFF) { src = pemb;  off = PEMB_OFF; }
    else if (i < A2HW_OFF) { src = h2a_w; off = H2AW_OFF; }
    else                   { src = a2h_w; off = A2HW_OFF; }
    ws[i] = f2b(src[i - off]);
}

// ---------- kernel 2: main (v15 == v13, the measured-best configuration) ------
// R14 post-mortem: Phase-D wave-split + its extra __syncthreads regressed 93->100us
// (barrier drain > ILP gain at 12 waves/CU). Reverted wholesale; v13 is the floor
// configuration: 4 barriers, DPP reductions, packed-f32 dot, strength-reduced addr.
__global__ __launch_bounds__(512, 6)
void CrossTeam_v15(const int* __restrict__ home, const int* __restrict__ away,
                   const int* __restrict__ hpos, const int* __restrict__ apos,
                   const u16* __restrict__ wsb,
                   const float* __restrict__ h2a_b,
                   const float* __restrict__ h2a_ow, const float* __restrict__ h2a_ob,
                   const float* __restrict__ a2h_b,
                   const float* __restrict__ a2h_ow, const float* __restrict__ a2h_ob,
                   const float* __restrict__ gw, const float* __restrict__ gb,
                   const float* __restrict__ lnw, const float* __restrict__ lnb,
                   float* __restrict__ out)
{
    // proj: 0=Qh 1=Kh 2=Vh 3=Qa 4=Ka 5=Va (bf16, bias folded, sample-major,
    // 16B chunks XOR-swizzled by row&3)
    __shared__ u16 proj[6][NR * 32];          // 33792 B
    __shared__ union {
        int ptab[2][NR][2];                   // 2816 B (Phase A-B): {player, pos}
        struct {                              // 4096 B (Phase C-D)
            float obuf[2][RPB][32];
            float ybuf[2][RPB][32];
        } cd;
    } u;
    __shared__ u32 mraw[2][RPB];              //    64 B   -> 37952 B total

    const int t = threadIdx.x;
    const int b0 = blockIdx.x * RPB;

    // ---- Phase A: stage indices + padding masks ----
    if (t < 176) {
        const int side = t / 88;              // 0 = home, 1 = away
        const int s = t - side * 88;          // sample = r*11 + l
        const int r = s / 11, l = s - r * 11;
        const int gi = (b0 + r) * LQ + l;
        u.ptab[side][s][0] = side ? away[gi] : home[gi];
        u.ptab[side][s][1] = side ? apos[gi] : hpos[gi];
    }
    if (t >= 496) {
        const int k = t - 496; const int side = k >> 3; const int r = k & 7;
        const int* arr = side ? away : home;
        u32 m = 0;
        for (int l = 0; l < LQ; ++l) m |= (u32)(arr[(b0 + r) * LQ + l] == 0) << l;
        mraw[side][r] = m;
    }
    __syncthreads();

    const int wave = t >> 6, lane = t & 63;
    const int lq = lane >> 4, lm = lane & 15;  // quad, in-tile index

    // ---- Phase B: QKV projections via MFMA; fragments load pre-packed bf16 ----
    {
        const int side = wave >> 2;            // which x-vectors (0=h, 1=a)
        const int mh = (wave >> 1) & 1;        // M-tile half
        const int nh = wave & 1;               // N-tile half
        // h-vectors: Q from h2a.Wq, K/V from a2h.Wk/Wv; a-vectors vice versa
        const u16* wq_src  = wsb + (side ? A2HW_OFF : H2AW_OFF);
        const u16* wkv_src = wsb + (side ? H2AW_OFF : A2HW_OFF);
        const float* bq_src  = side ? a2h_b : h2a_b;
        const float* bkv_src = side ? h2a_b : a2h_b;
        bf16x8 afrag[3]; float bias[3][4];
        #pragma unroll
        for (int i = 0; i < 3; ++i) {
            const int M = (mh * 3 + i) * 16;
            const u16* wsrc = (M < 32) ? wq_src : wkv_src;
            afrag[i] = *(const bf16x8*)(wsrc + (M + lm) * 32 + lq * 8);
            const float* bs = (M < 32) ? bq_src : bkv_src;
            #pragma unroll
            for (int j = 0; j < 4; ++j) bias[i][j] = bs[M + lq * 4 + j];
        }
        bf16x8 bfrag[3];
        #pragma unroll
        for (int nn = 0; nn < 3; ++nn) {
            const int srow = (nh * 3 + nn) * 16 + lm;
            const int s = srow < NR ? srow : NR - 1;     // cols >=88 discarded at store
            const int id = u.ptab[side][s][lq >> 1];     // quads 0-1: player, 2-3: pos
            bfrag[nn] = *(const bf16x8*)
                (wsb + ((lq < 2) ? EMB_OFF : PEMB_OFF) + id * 16 + (lq & 1) * 8);
        }
        #pragma unroll
        for (int nn = 0; nn < 3; ++nn) {
            const int srow = (nh * 3 + nn) * 16 + lm;
            #pragma unroll
            for (int i = 0; i < 3; ++i) {
                f32x4 acc = { bias[i][0], bias[i][1], bias[i][2], bias[i][3] };
                acc = __builtin_amdgcn_mfma_f32_16x16x32_bf16(afrag[i], bfrag[nn], acc, 0, 0, 0);
                const int mt = mh * 3 + i;
                const int mat = side * 3 + (mt >> 1);      // Q/K/V of this side
                const int dimw = (mt & 1) * 16 + lq * 4;   // u16 index within 32
                if (srow < NR) {
                    const int phys = srow * 32 + ((((dimw >> 3) ^ srow) & 3) << 3) + (dimw & 7);
                    uint2 pk;
                    pk.x = pk2(acc[0], acc[1]);
                    pk.y = pk2(acc[2], acc[3]);
                    *(uint2*)&proj[mat][phys] = pk;
                }
            }
        }
    }
    __syncthreads();

    // ---- Phase C: attention + query-mean aggregation, lane = (head, qi) ----
    // ki regrouped by kb = ki mod 4: same swizzle phase -> base ptr + m*256B
    // immediate offsets (no per-ki XOR address math). Dot in f32x2 (pk-f32 path).
    {
        const int hh = lane >> 4;              // head
        const int slot = lane & 15;            // qi slot (>=11 inactive)
        const int qi = slot < 11 ? slot : 10;  // clamped for safe loads
        const int dpv = hh * 8 + (slot & 7);   // PV output dim for this lane
        #pragma unroll
        for (int it = 0; it < 2; ++it) {
            const int task = wave * 2 + it;               // 16 tasks over 8 waves
            const int r = task >> 1, dir = task & 1;      // 0: h2a, 1: a2h
            const int qmat = dir ? 3 : 0;
            const int kmat = dir ? 1 : 4;
            const int vmat = dir ? 2 : 5;
            const int r11 = r * 11;
            const u32 kvraw = mraw[dir ? 0 : 1][r];       // KV-side padding mask
            const u32 kv = (kvraw == 0x7FFu) ? 0u : kvraw;   // safe_mask
            const u32 qraw = mraw[dir ? 1 : 0][r];        // query-side mask
            const u32 smq = (qraw == 0x7FFu) ? 0u : qraw;
            const u32 vm = (~smq) & 0x7FFu;               // valid queries (never empty)
            const float invc = 1.0f / (float)__popc(vm);
            const float wqw = (slot < 11 && ((vm >> slot) & 1u)) ? invc : 0.f;
            const int qrow = r11 + qi;
            const uint4 qp = *(const uint4*)&proj[qmat][qrow * 32 + (((hh ^ qrow) & 3) << 3)];
            const f32x2 sc2 = { 0.35355339059327373f, 0.35355339059327373f };
            f32x2 qv2[4];                                  // 1/sqrt(8) pre-folded
            qv2[0] = kf2(qp.x) * sc2; qv2[1] = kf2(qp.y) * sc2;
            qv2[2] = kf2(qp.z) * sc2; qv2[3] = kf2(qp.w) * sc2;
            float e[11]; float sum = 0.f;
            #pragma unroll
            for (int kb = 0; kb < 4; ++kb) {
                const int krow0 = r11 + kb;
                const u16* kbp = &proj[kmat][krow0 * 32 + (((hh ^ krow0) & 3) << 3)];
                #pragma unroll
                for (int m = 0; m < 3; ++m) {
                    const int ki = kb + 4 * m;            // compile-time constant
                    if (ki < 11) {
                        const uint4 kp = *(const uint4*)(kbp + m * 128);  // +256B imm
                        f32x2 acc = qv2[0] * kf2(kp.x);
                        acc += qv2[1] * kf2(kp.y);
                        acc += qv2[2] * kf2(kp.z);
                        acc += qv2[3] * kf2(kp.w);
                        const float s = acc[0] + acc[1];
                        e[ki] = ((kv >> ki) & 1u) ? 0.f : __expf(s);  // exact exp(-inf)=0
                        sum += e[ki];
                    }
                }
            }
            const float rs = wqw / fmaxf(sum, 1e-20f);    // fold aggregation weight in
            float o = 0.f;
            #pragma unroll
            for (int kb = 0; kb < 4; ++kb) {
                const int krow0 = r11 + kb;
                const u16* vbp = &proj[vmat][krow0 * 32 + (((hh ^ krow0) & 3) << 3) + (slot & 7)];
                #pragma unroll
                for (int m = 0; m < 3; ++m) {
                    const int ki = kb + 4 * m;
                    if (ki < 11) {
                        // sum w_q * p over the 16 qi slots: DPP butterfly (VALU-only)
                        const float v = qsum16(e[ki] * rs);
                        o += v * bf1(vbp[m * 128]);       // +256B imm offset
                    }
                }
            }
            if (slot < 8) u.cd.obuf[dir][r][dpv] = o;     // 32 dims per task
        }
    }
    __syncthreads();

    // ---- Phase D: out-proj + gate + LayerNorm (threads 0..255, f32x4 loads) ----
    if (t < 256) {
        const int r = t >> 5, d = t & 31;
        float yh = h2a_ob[d], ya = a2h_ob[d];
        {
            const f32x4* w0 = (const f32x4*)(h2a_ow + d * 32);
            const f32x4* w1 = (const f32x4*)(a2h_ow + d * 32);
            const f32x4* o0 = (const f32x4*)&u.cd.obuf[0][r][0];
            const f32x4* o1 = (const f32x4*)&u.cd.obuf[1][r][0];
            #pragma unroll
            for (int c = 0; c < 8; ++c) {
                const f32x4 a = o0[c], b = w0[c], p = o1[c], q = w1[c];
                yh += a[0]*b[0] + a[1]*b[1] + a[2]*b[2] + a[3]*b[3];
                ya += p[0]*q[0] + p[1]*q[1] + p[2]*q[2] + p[3]*q[3];
            }
        }
        u.cd.ybuf[0][r][d] = yh; u.cd.ybuf[1][r][d] = ya;
        // readers below are the same 32-lane group that wrote -> same-wave DS ordering
        float acc = gb[d];
        {
            const f32x4* g0 = (const f32x4*)(gw + d * 64);
            const f32x4* y0 = (const f32x4*)&u.cd.ybuf[0][r][0];
            const f32x4* y1 = (const f32x4*)&u.cd.ybuf[1][r][0];
            #pragma unroll
            for (int c = 0; c < 8; ++c) {
                const f32x4 a = y0[c], b = g0[c], p = y1[c], q = g0[8 + c];
                acc += a[0]*b[0] + a[1]*b[1] + a[2]*b[2] + a[3]*b[3];
                acc += p[0]*q[0] + p[1]*q[1] + p[2]*q[2] + p[3]*q[3];
            }
        }
        const float g = 1.0f / (1.0f + __expf(-acc));
        const float m = g * yh + (1.0f - g) * ya;
        // 32-wide reduction: DPP within 16, one shuffle across the halves
        float s1 = qsum16(m), s2 = qsum16(m * m);
        s1 += __shfl_xor(s1, 16, 32);
        s2 += __shfl_xor(s2, 16, 32);
        const float mu = s1 * 0.03125f;
        const float var = fmaxf(s2 * 0.03125f - mu * mu, 0.f);
        const float res = (m - mu) * rsqrtf(var + 1e-5f) * lnw[d] + lnb[d];
        out[(b0 + r) * 32 + d] = res;
    }
}

// ---------- fallback (ws too small): proven v9, byte-identical ----------
__global__ __launch_bounds__(512, 6)
void CrossTeam_v9fb(const int* __restrict__ home, const int* __restrict__ away,
                    const int* __restrict__ hpos, const int* __restrict__ apos,
                    const float* __restrict__ emb, const float* __restrict__ pemb,
                    const float* __restrict__ h2a_w, const float* __restrict__ h2a_b,
                    const float* __restrict__ h2a_ow, const float* __restrict__ h2a_ob,
                    const float* __restrict__ a2h_w, const float* __restrict__ a2h_b,
                    const float* __restrict__ a2h_ow, const float* __restrict__ a2h_ob,
                    const float* __restrict__ gw, const float* __restrict__ gb,
                    const float* __restrict__ lnw, const float* __restrict__ lnb,
                    float* __restrict__ out)
{
    __shared__ u16 proj[6][NR * 32];
    __shared__ union {
        int ptab[2][NR][2];
        struct { float obuf[2][RPB][32]; float ybuf[2][RPB][32]; } cd;
    } u;
    __shared__ u32 mraw[2][RPB];
    const int t = threadIdx.x;
    const int b0 = blockIdx.x * RPB;
    if (t < 176) {
        const int side = t / 88, s = t - side * 88;
        const int r = s / 11, l = s - r * 11;
        const int gi = (b0 + r) * LQ + l;
        u.ptab[side][s][0] = side ? away[gi] : home[gi];
        u.ptab[side][s][1] = side ? apos[gi] : hpos[gi];
    }
    if (t >= 496) {
        const int k = t - 496; const int side = k >> 3; const int r = k & 7;
        const int* arr = side ? away : home;
        u32 m = 0;
        for (int l = 0; l < LQ; ++l) m |= (u32)(arr[(b0 + r) * LQ + l] == 0) << l;
        mraw[side][r] = m;
    }
    __syncthreads();
    const int wave = t >> 6, lane = t & 63;
    const int lq = lane >> 4, lm = lane & 15;
    {
        const int side = wave >> 2, mh = (wave >> 1) & 1, nh = wave & 1;
        const float* wq_src  = side ? a2h_w : h2a_w;
        const float* wkv_src = side ? h2a_w : a2h_w;
        const float* bq_src  = side ? a2h_b : h2a_b;
        const float* bkv_src = side ? h2a_b : a2h_b;
        bf16x8 afrag[3]; float bias[3][4];
        #pragma unroll
        for (int i = 0; i < 3; ++i) {
            const int M = (mh * 3 + i) * 16;
            const float* ws = (M < 32) ? wq_src : wkv_src;
            const float* wp = ws + (M + lm) * 32 + lq * 8;
            const f32x4 a0 = *(const f32x4*)wp;
            const f32x4 a1 = *(const f32x4*)(wp + 4);
            union { bf16x8 v; u32 w[4]; } au;
            au.w[0] = pk2(a0[0], a0[1]); au.w[1] = pk2(a0[2], a0[3]);
            au.w[2] = pk2(a1[0], a1[1]); au.w[3] = pk2(a1[2], a1[3]);
            afrag[i] = au.v;
            const float* bs = (M < 32) ? bq_src : bkv_src;
            #pragma unroll
            for (int j = 0; j < 4; ++j) bias[i][j] = bs[M + lq * 4 + j];
        }
        bf16x8 bfrag[3];
        #pragma unroll
        for (int nn = 0; nn < 3; ++nn) {
            const int srow = (nh * 3 + nn) * 16 + lm;
            const int s = srow < NR ? srow : NR - 1;
            const int id = u.ptab[side][s][lq >> 1];
            const float* gp = ((lq < 2) ? emb : pemb) + id * 16 + (lq & 1) * 8;
            const f32x4 g0 = *(const f32x4*)gp;
            const f32x4 g1 = *(const f32x4*)(gp + 4);
            union { bf16x8 v; u32 w[4]; } bu;
            bu.w[0] = pk2(g0[0], g0[1]); bu.w[1] = pk2(g0[2], g0[3]);
            bu.w[2] = pk2(g1[0], g1[1]); bu.w[3] = pk2(g1[2], g1[3]);
            bfrag[nn] = bu.v;
        }
        #pragma unroll
        for (int nn = 0; nn < 3; ++nn) {
            const int srow = (nh * 3 + nn) * 16 + lm;
            #pragma unroll
            for (int i = 0; i < 3; ++i) {
                f32x4 acc = { bias[i][0], bias[i][1], bias[i][2], bias[i][3] };
                acc = __builtin_amdgcn_mfma_f32_16x16x32_bf16(afrag[i], bfrag[nn], acc, 0, 0, 0);
                const int mt = mh * 3 + i;
                const int mat = side * 3 + (mt >> 1);
                const int dimw = (mt & 1) * 16 + lq * 4;
                if (srow < NR) {
                    const int phys = srow * 32 + ((((dimw >> 3) ^ srow) & 3) << 3) + (dimw & 7);
                    uint2 pk; pk.x = pk2(acc[0], acc[1]); pk.y = pk2(acc[2], acc[3]);
                    *(uint2*)&proj[mat][phys] = pk;
                }
            }
        }
    }
    __syncthreads();
    {
        const int hh = lane >> 4, slot = lane & 15;
        const int qi = slot < 11 ? slot : 10;
        const int dpv = hh * 8 + (slot & 7);
        #pragma unroll
        for (int it = 0; it < 2; ++it) {
            const int task = wave * 2 + it;
            const int r = task >> 1, dir = task & 1;
            const int qmat = dir ? 3 : 0, kmat = dir ? 1 : 4, vmat = dir ? 2 : 5;
            const int r11 = r * 11;
            const u32 kvraw = mraw[dir ? 0 : 1][r];
            const u32 kv = (kvraw == 0x7FFu) ? 0u : kvraw;
            const u32 qraw = mraw[dir ? 1 : 0][r];
            const u32 smq = (qraw == 0x7FFu) ? 0u : qraw;
            const u32 vm = (~smq) & 0x7FFu;
            const float invc = 1.0f / (float)__popc(vm);
            const float wqw = (slot < 11 && ((vm >> slot) & 1u)) ? invc : 0.f;
            const int qrow = r11 + qi;
            const uint4 qp = *(const uint4*)&proj[qmat][qrow * 32 + (((hh ^ qrow) & 3) << 3)];
            float qv[8];
            qv[0]=blo(qp.x); qv[1]=bhi(qp.x); qv[2]=blo(qp.y); qv[3]=bhi(qp.y);
            qv[4]=blo(qp.z); qv[5]=bhi(qp.z); qv[6]=blo(qp.w); qv[7]=bhi(qp.w);
            float e[11]; float sum = 0.f;
            #pragma unroll
            for (int ki = 0; ki < 11; ++ki) {
                const int krow = r11 + ki;
                const uint4 kp = *(const uint4*)&proj[kmat][krow * 32 + (((hh ^ krow) & 3) << 3)];
                float s = qv[0]*blo(kp.x) + qv[1]*bhi(kp.x) + qv[2]*blo(kp.y) + qv[3]*bhi(kp.y)
                        + qv[4]*blo(kp.z) + qv[5]*bhi(kp.z) + qv[6]*blo(kp.w) + qv[7]*bhi(kp.w);
                s *= 0.35355339059327373f;
                e[ki] = ((kv >> ki) & 1u) ? 0.f : __expf(s);
                sum += e[ki];
            }
            const float rs = wqw / fmaxf(sum, 1e-20f);
            float o = 0.f;
            #pragma unroll
            for (int ki = 0; ki < 11; ++ki) {
                float v = e[ki] * rs;
                v += __shfl_xor(v, 1, 16); v += __shfl_xor(v, 2, 16);
                v += __shfl_xor(v, 4, 16); v += __shfl_xor(v, 8, 16);
                const int vrow = r11 + ki;
                o += v * bf1(proj[vmat][vrow * 32 + (((hh ^ vrow) & 3) << 3) + (slot & 7)]);
            }
            if (slot < 8) u.cd.obuf[dir][r][dpv] = o;
        }
    }
    __syncthreads();
    if (t < 256) {
        const int r = t >> 5, d = t & 31;
        float yh = h2a_ob[d];
        const float* wr = h2a_ow + d * 32;
        #pragma unroll
        for (int c = 0; c < 32; ++c) yh += u.cd.obuf[0][r][c] * wr[c];
        float ya = a2h_ob[d];
        wr = a2h_ow + d * 32;
        #pragma unroll
        for (int c = 0; c < 32; ++c) ya += u.cd.obuf[1][r][c] * wr[c];
        u.cd.ybuf[0][r][d] = yh; u.cd.ybuf[1][r][d] = ya;
        float acc = gb[d];
        const float* gr = gw + d * 64;
        #pragma unroll
        for (int c = 0; c < 32; ++c) acc += u.cd.ybuf[0][r][c] * gr[c];
        #pragma unroll
        for (int c = 0; c < 32; ++c) acc += u.cd.ybuf[1][r][c] * gr[32 + c];
        const float g = 1.0f / (1.0f + __expf(-acc));
        const float m = g * yh + (1.0f - g) * ya;
        float s1 = m, s2 = m * m;
        #pragma unroll
        for (int off = 1; off < 32; off <<= 1) {
            s1 += __shfl_xor(s1, off, 32); s2 += __shfl_xor(s2, off, 32);
        }
        const float mu = s1 * 0.03125f;
        const float var = fmaxf(s2 * 0.03125f - mu * mu, 0.f);
        out[(b0 + r) * 32 + d] = (m - mu) * rsqrtf(var + 1e-5f) * lnw[d] + lnb[d];
    }
}

extern "C" void kernel_launch(void* const* d_in, const int* in_sizes, int n_in,
                              void* d_out, int out_size, void* d_ws, size_t ws_size,
                              hipStream_t stream) {
    (void)in_sizes; (void)n_in; (void)out_size;
    if (ws_size >= (size_t)PACK_N * 2) {
        pack_tables<<<(PACK_N + 255) / 256, 256, 0, stream>>>(
            (const float*)d_in[4], (const float*)d_in[5],
            (const float*)d_in[6], (const float*)d_in[10], (u16*)d_ws);
        CrossTeam_v15<<<32768 / RPB, 512, 0, stream>>>(
            (const int*)d_in[0], (const int*)d_in[1], (const int*)d_in[2], (const int*)d_in[3],
            (const u16*)d_ws,
            (const float*)d_in[7], (const float*)d_in[8], (const float*)d_in[9],
            (const float*)d_in[11], (const float*)d_in[12], (const float*)d_in[13],
            (const float*)d_in[14], (const float*)d_in[15], (const float*)d_in[16],
            (const float*)d_in[17], (float*)d_out);
    } else {
        CrossTeam_v9fb<<<32768 / RPB, 512, 0, stream>>>(
            (const int*)d_in[0], (const int*)d_in[1], (const int*)d_in[2], (const int*)d_in[3],
            (const float*)d_in[4], (const float*)d_in[5],
            (const float*)d_in[6], (const float*)d_in[7], (const float*)d_in[8], (const float*)d_in[9],
            (const float*)d_in[10], (const float*)d_in[11], (const float*)d_in[12], (const float*)d_in[13],
            (const float*)d_in[14], (const float*)d_in[15], (const float*)d_in[16], (const float*)d_in[17],
            (float*)d_out);
    }
}